// Round 2
// baseline (1312.097 us; speedup 1.0000x reference)
//
#include <hip/hip_runtime.h>

// GCN 2-layer forward, all-float32 wire format, edge_index int32.
// out[i] = sum_{(j,i) in E} dinv[j]*dinv[i]*h[j] + dinv[i]^2*h[i] + b
// deg[i] = (#edges with col==i) + 1 (self loop), dinv = rsqrt(deg).

#define DIN 128
#define DHID 128
#define DOUT 64

// ---------------- degree ----------------
__global__ void k_deg(const int* __restrict__ cols, int* __restrict__ deg, int E) {
    int i = blockIdx.x * blockDim.x + threadIdx.x;
    if (i < E) atomicAdd(&deg[cols[i]], 1);
}

__global__ void k_dinv(const int* __restrict__ deg, float* __restrict__ dinv, int N) {
    int i = blockIdx.x * blockDim.x + threadIdx.x;
    if (i < N) dinv[i] = rsqrtf((float)(deg[i] + 1));
}

// ---------------- GEMM1: h1[N,128] = x[N,128] @ W1[128,128] ----------------
// Block 256 = 4 waves; block does 16 rows; wave does 4 rows; lane owns cols {l, l+64}.
__global__ __launch_bounds__(256) void k_gemm1(const float* __restrict__ x,
                                               const float* __restrict__ W,
                                               float* __restrict__ h, int N) {
    __shared__ float xs[16][DIN];
    int t = threadIdx.x;
    int rowBase = blockIdx.x * 16;
    {
        int li = t * 8;                 // 256 threads x 8 floats (two float4)
        int lr = li >> 7, lc = li & 127;
        int gr = rowBase + lr;
        if (gr < N) {
            const float4* src = (const float4*)(x + (size_t)gr * DIN + lc);
            float4 a = src[0], b = src[1];
            *(float4*)&xs[lr][lc] = a;
            *(float4*)&xs[lr][lc + 4] = b;
        }
    }
    __syncthreads();
    int wave = t >> 6, lane = t & 63;
    int r0 = rowBase + wave * 4;
    float acc[4][2] = {{0.f, 0.f}, {0.f, 0.f}, {0.f, 0.f}, {0.f, 0.f}};
#pragma unroll 4
    for (int k = 0; k < DIN; ++k) {
        float w0 = W[k * DHID + lane];
        float w1 = W[k * DHID + 64 + lane];
#pragma unroll
        for (int r = 0; r < 4; ++r) {
            float xv = xs[wave * 4 + r][k];
            acc[r][0] = fmaf(xv, w0, acc[r][0]);
            acc[r][1] = fmaf(xv, w1, acc[r][1]);
        }
    }
#pragma unroll
    for (int r = 0; r < 4; ++r) {
        int gr = r0 + r;
        if (gr < N) {
            h[(size_t)gr * DHID + lane]      = acc[r][0];
            h[(size_t)gr * DHID + 64 + lane] = acc[r][1];
        }
    }
}

// ---------------- scatter layer 1: agg1[c,:] += w * h1[r,:] (128 dims) ----------------
// one wave per edge; lane handles dims {l, l+64}
__global__ __launch_bounds__(256) void k_scatter1(const int* __restrict__ rows,
                                                  const int* __restrict__ cols,
                                                  const float* __restrict__ dinv,
                                                  const float* __restrict__ h1,
                                                  float* __restrict__ agg1, int E) {
    int gid = blockIdx.x * 256 + threadIdx.x;
    int w = gid >> 6, lane = gid & 63;
    if (w >= E) return;
    int r = rows[w], c = cols[w];
    float nw = dinv[r] * dinv[c];
    float v0 = h1[(size_t)r * DHID + lane] * nw;
    float v1 = h1[(size_t)r * DHID + 64 + lane] * nw;
    atomicAdd(&agg1[(size_t)c * DHID + lane], v0);
    atomicAdd(&agg1[(size_t)c * DHID + 64 + lane], v1);
}

// ---------------- bias + self-loop + relu; h1 <- relu(agg1 + dinv^2*h1 + b1) ----------------
__global__ void k_act(const float* __restrict__ agg1, float* __restrict__ h1,
                      const float* __restrict__ b1, const float* __restrict__ dinv, int N) {
    int i = blockIdx.x * blockDim.x + threadIdx.x;
    if (i >= N * DHID) return;
    int node = i >> 7, c = i & 127;
    float dd = dinv[node]; dd *= dd;
    float v = agg1[i] + dd * h1[i] + b1[c];
    h1[i] = fmaxf(v, 0.f);
}

// ---------------- GEMM2: h2[N,64] = hact[N,128] @ W2[128,64] ----------------
// Block 256 = 4 waves; block does 16 rows; wave does 4 rows; lane owns col `lane`.
__global__ __launch_bounds__(256) void k_gemm2(const float* __restrict__ hact,
                                               const float* __restrict__ W,
                                               float* __restrict__ h2, int N) {
    __shared__ float xs[16][DHID];
    int t = threadIdx.x;
    int rowBase = blockIdx.x * 16;
    {
        int li = t * 8;
        int lr = li >> 7, lc = li & 127;
        int gr = rowBase + lr;
        if (gr < N) {
            const float4* src = (const float4*)(hact + (size_t)gr * DHID + lc);
            float4 a = src[0], b = src[1];
            *(float4*)&xs[lr][lc] = a;
            *(float4*)&xs[lr][lc + 4] = b;
        }
    }
    __syncthreads();
    int wave = t >> 6, lane = t & 63;
    int r0 = rowBase + wave * 4;
    float a0 = 0.f, a1 = 0.f, a2 = 0.f, a3 = 0.f;
#pragma unroll 4
    for (int k = 0; k < DHID; ++k) {
        float wk = W[k * DOUT + lane];
        a0 = fmaf(xs[wave * 4 + 0][k], wk, a0);
        a1 = fmaf(xs[wave * 4 + 1][k], wk, a1);
        a2 = fmaf(xs[wave * 4 + 2][k], wk, a2);
        a3 = fmaf(xs[wave * 4 + 3][k], wk, a3);
    }
    if (r0 + 0 < N) h2[(size_t)(r0 + 0) * DOUT + lane] = a0;
    if (r0 + 1 < N) h2[(size_t)(r0 + 1) * DOUT + lane] = a1;
    if (r0 + 2 < N) h2[(size_t)(r0 + 2) * DOUT + lane] = a2;
    if (r0 + 3 < N) h2[(size_t)(r0 + 3) * DOUT + lane] = a3;
}

// ---------------- scatter layer 2: out[c,:] += w * h2[r,:] (64 dims) ----------------
__global__ __launch_bounds__(256) void k_scatter2(const int* __restrict__ rows,
                                                  const int* __restrict__ cols,
                                                  const float* __restrict__ dinv,
                                                  const float* __restrict__ h2,
                                                  float* __restrict__ out, int E) {
    int gid = blockIdx.x * 256 + threadIdx.x;
    int w = gid >> 6, lane = gid & 63;
    if (w >= E) return;
    int r = rows[w], c = cols[w];
    float nw = dinv[r] * dinv[c];
    float v = h2[(size_t)r * DOUT + lane] * nw;
    atomicAdd(&out[(size_t)c * DOUT + lane], v);
}

// ---------------- final epilogue in place on d_out: out += dinv^2*h2 + b2 ----------------
__global__ void k_out(float* __restrict__ out, const float* __restrict__ h2,
                      const float* __restrict__ b2, const float* __restrict__ dinv, int N) {
    int i = blockIdx.x * blockDim.x + threadIdx.x;
    if (i >= N * DOUT) return;
    int node = i >> 6, c = i & 63;
    float dd = dinv[node]; dd *= dd;
    out[i] = out[i] + dd * h2[i] + b2[c];
}

extern "C" void kernel_launch(void* const* d_in, const int* in_sizes, int n_in,
                              void* d_out, int out_size, void* d_ws, size_t ws_size,
                              hipStream_t stream) {
    const float* x  = (const float*)d_in[0];
    const int*   ei = (const int*)d_in[1];
    const float* W1 = (const float*)d_in[2];
    const float* b1 = (const float*)d_in[3];
    const float* W2 = (const float*)d_in[4];
    const float* b2 = (const float*)d_in[5];

    const int N = in_sizes[0] / DIN;     // 100000
    const int E = in_sizes[1] / 2;       // 1600000
    const int* rows = ei;                // edge_index[0] = sources
    const int* cols = ei + E;            // edge_index[1] = destinations

    // workspace layout (~103 MB)
    char* p = (char*)d_ws;
    float* h1   = (float*)p;  p += (size_t)N * DHID * 4;   // 51.2 MB
    float* agg1 = (float*)p;  p += (size_t)N * DHID * 4;   // 51.2 MB (reused as h2)
    float* dinv = (float*)p;  p += (size_t)N * 4;
    int*   deg  = (int*)p;    p += (size_t)N * 4;
    float* h2   = agg1;                                    // alias: agg1 dead after k_act
    float* outF = (float*)d_out;                           // agg2 accumulates in d_out

    // degree + dinv
    hipMemsetAsync(deg, 0, (size_t)N * 4, stream);
    k_deg<<<(E + 255) / 256, 256, 0, stream>>>(cols, deg, E);
    k_dinv<<<(N + 255) / 256, 256, 0, stream>>>(deg, dinv, N);

    // layer 1
    k_gemm1<<<(N + 15) / 16, 256, 0, stream>>>(x, W1, h1, N);
    hipMemsetAsync(agg1, 0, (size_t)N * DHID * 4, stream);
    k_scatter1<<<(E * 64 + 255) / 256, 256, 0, stream>>>(rows, cols, dinv, h1, agg1, E);
    k_act<<<(N * DHID + 255) / 256, 256, 0, stream>>>(agg1, h1, b1, dinv, N);

    // layer 2 (h2 overwrites agg1's buffer — agg1 consumed by k_act)
    k_gemm2<<<(N + 15) / 16, 256, 0, stream>>>(h1, W2, h2, N);
    hipMemsetAsync(outF, 0, (size_t)N * DOUT * 4, stream);
    k_scatter2<<<(E * 64 + 255) / 256, 256, 0, stream>>>(rows, cols, dinv, h2, outF, E);
    k_out<<<(N * DOUT + 255) / 256, 256, 0, stream>>>(outF, h2, b2, dinv, N);
}

// Round 3
// 640.500 us; speedup vs baseline: 2.0486x; 2.0486x over previous
//
#include <hip/hip_runtime.h>

// GCN 2-layer forward, all-float32, edge_index int32.
// out[i] = di * sum_{(j,i) in E} dj*h[j] + di^2*h[i] + b   (di = rsqrt(deg_i+1))
// Strategy: build CSR by destination once (no float atomics), then register-
// accumulating gathers with fused epilogues.

#define DIN 128
#define DHID 128
#define DOUT 64
#define SCAN_CHUNK 1024

// ---------------- degree histogram ----------------
__global__ void k_deg(const int* __restrict__ cols, int* __restrict__ deg, int E) {
    int i = blockIdx.x * blockDim.x + threadIdx.x;
    if (i < E) atomicAdd(&deg[cols[i]], 1);
}

__global__ void k_dinv(const int* __restrict__ deg, float* __restrict__ dinv, int N) {
    int i = blockIdx.x * blockDim.x + threadIdx.x;
    if (i < N) dinv[i] = rsqrtf((float)(deg[i] + 1));
}

// ---------------- exclusive scan (two-kernel, 1024 elems/block) ----------------
__global__ __launch_bounds__(256) void k_partial(const int* __restrict__ cnt,
                                                 int* __restrict__ partials, int N) {
    __shared__ int s[256];
    int b = blockIdx.x, t = threadIdx.x;
    int base = b * SCAN_CHUNK + t * 4;
    int sum = 0;
#pragma unroll
    for (int i = 0; i < 4; ++i) { int idx = base + i; if (idx < N) sum += cnt[idx]; }
    s[t] = sum; __syncthreads();
    for (int off = 128; off > 0; off >>= 1) { if (t < off) s[t] += s[t + off]; __syncthreads(); }
    if (t == 0) partials[b] = s[0];
}

// assumes nblk <= 256
__global__ __launch_bounds__(256) void k_scan(const int* __restrict__ cnt,
                                              const int* __restrict__ partials,
                                              int* __restrict__ rowptr, int N, int nblk) {
    __shared__ int s[256];
    int b = blockIdx.x, t = threadIdx.x;
    // block offset = sum partials[0..b)
    s[t] = (t < b && t < nblk) ? partials[t] : 0;
    __syncthreads();
    for (int off = 128; off > 0; off >>= 1) { if (t < off) s[t] += s[t + off]; __syncthreads(); }
    int blockOff = s[0];
    __syncthreads();
    // per-thread 4 values
    int base = b * SCAN_CHUNK + t * 4;
    int v[4]; int sum = 0;
#pragma unroll
    for (int i = 0; i < 4; ++i) { int idx = base + i; v[i] = (idx < N) ? cnt[idx] : 0; sum += v[i]; }
    s[t] = sum; __syncthreads();
    // inclusive scan over 256 thread-sums
    for (int off = 1; off < 256; off <<= 1) {
        int x = s[t]; if (t >= off) x += s[t - off];
        __syncthreads(); s[t] = x; __syncthreads();
    }
    int run = blockOff + (t == 0 ? 0 : s[t - 1]);
#pragma unroll
    for (int i = 0; i < 4; ++i) {
        int idx = base + i;
        if (idx < N) rowptr[idx] = run;
        run += v[i];
        if (idx == N - 1) rowptr[N] = run;   // == E
    }
}

// ---------------- bucket edges into CSR order ----------------
__global__ void k_bucket(const int* __restrict__ rows, const int* __restrict__ cols,
                         int* __restrict__ cursor, int* __restrict__ srcs, int E) {
    int e = blockIdx.x * blockDim.x + threadIdx.x;
    if (e >= E) return;
    int c = cols[e];
    int pos = atomicAdd(&cursor[c], 1);
    srcs[pos] = rows[e];
}

// ---------------- GEMM1: h1[N,128] = x[N,128] @ W1[128,128] ----------------
__global__ __launch_bounds__(256) void k_gemm1(const float* __restrict__ x,
                                               const float* __restrict__ W,
                                               float* __restrict__ h, int N) {
    __shared__ float xs[16][DIN];
    int t = threadIdx.x;
    int rowBase = blockIdx.x * 16;
    {
        int li = t * 8;
        int lr = li >> 7, lc = li & 127;
        int gr = rowBase + lr;
        if (gr < N) {
            const float4* src = (const float4*)(x + (size_t)gr * DIN + lc);
            float4 a = src[0], b = src[1];
            *(float4*)&xs[lr][lc] = a;
            *(float4*)&xs[lr][lc + 4] = b;
        }
    }
    __syncthreads();
    int wave = t >> 6, lane = t & 63;
    int r0 = rowBase + wave * 4;
    float acc[4][2] = {{0.f,0.f},{0.f,0.f},{0.f,0.f},{0.f,0.f}};
#pragma unroll 4
    for (int k = 0; k < DIN; ++k) {
        float w0 = W[k * DHID + lane];
        float w1 = W[k * DHID + 64 + lane];
#pragma unroll
        for (int r = 0; r < 4; ++r) {
            float xv = xs[wave * 4 + r][k];
            acc[r][0] = fmaf(xv, w0, acc[r][0]);
            acc[r][1] = fmaf(xv, w1, acc[r][1]);
        }
    }
#pragma unroll
    for (int r = 0; r < 4; ++r) {
        int gr = r0 + r;
        if (gr < N) {
            h[(size_t)gr * DHID + lane]      = acc[r][0];
            h[(size_t)gr * DHID + 64 + lane] = acc[r][1];
        }
    }
}

// ---------------- gather layer 1 + fused bias/self-loop/relu ----------------
// one wave per destination node; lane owns dims {2l, 2l+1} (float2)
__global__ __launch_bounds__(256) void k_gather1(const int* __restrict__ rowptr,
                                                 const int* __restrict__ srcs,
                                                 const float* __restrict__ dinv,
                                                 const float* __restrict__ h1,
                                                 const float* __restrict__ b1,
                                                 float* __restrict__ hact, int N) {
    int w = (blockIdx.x * 256 + threadIdx.x) >> 6;
    int lane = threadIdx.x & 63;
    if (w >= N) return;
    int beg = rowptr[w], end = rowptr[w + 1];
    float a0 = 0.f, a1 = 0.f;
    int e = beg;
    for (; e + 1 < end; e += 2) {
        int s0 = srcs[e], s1 = srcs[e + 1];
        float d0 = dinv[s0], d1 = dinv[s1];
        float2 v0 = *(const float2*)(h1 + (size_t)s0 * DHID + 2 * lane);
        float2 v1 = *(const float2*)(h1 + (size_t)s1 * DHID + 2 * lane);
        a0 = fmaf(d0, v0.x, a0); a1 = fmaf(d0, v0.y, a1);
        a0 = fmaf(d1, v1.x, a0); a1 = fmaf(d1, v1.y, a1);
    }
    if (e < end) {
        int s0 = srcs[e];
        float d0 = dinv[s0];
        float2 v0 = *(const float2*)(h1 + (size_t)s0 * DHID + 2 * lane);
        a0 = fmaf(d0, v0.x, a0); a1 = fmaf(d0, v0.y, a1);
    }
    float di = dinv[w], self = di * di;
    float2 hv = *(const float2*)(h1 + (size_t)w * DHID + 2 * lane);
    float2 bv = *(const float2*)(b1 + 2 * lane);
    float r0 = fmaf(di, a0, fmaf(self, hv.x, bv.x));
    float r1 = fmaf(di, a1, fmaf(self, hv.y, bv.y));
    float2 out; out.x = fmaxf(r0, 0.f); out.y = fmaxf(r1, 0.f);
    *(float2*)(hact + (size_t)w * DHID + 2 * lane) = out;
}

// ---------------- GEMM2: h2[N,64] = hact[N,128] @ W2[128,64] ----------------
__global__ __launch_bounds__(256) void k_gemm2(const float* __restrict__ hact,
                                               const float* __restrict__ W,
                                               float* __restrict__ h2, int N) {
    __shared__ float xs[16][DHID];
    int t = threadIdx.x;
    int rowBase = blockIdx.x * 16;
    {
        int li = t * 8;
        int lr = li >> 7, lc = li & 127;
        int gr = rowBase + lr;
        if (gr < N) {
            const float4* src = (const float4*)(hact + (size_t)gr * DHID + lc);
            float4 a = src[0], b = src[1];
            *(float4*)&xs[lr][lc] = a;
            *(float4*)&xs[lr][lc + 4] = b;
        }
    }
    __syncthreads();
    int wave = t >> 6, lane = t & 63;
    int r0 = rowBase + wave * 4;
    float a0 = 0.f, a1 = 0.f, a2 = 0.f, a3 = 0.f;
#pragma unroll 4
    for (int k = 0; k < DHID; ++k) {
        float wk = W[k * DOUT + lane];
        a0 = fmaf(xs[wave * 4 + 0][k], wk, a0);
        a1 = fmaf(xs[wave * 4 + 1][k], wk, a1);
        a2 = fmaf(xs[wave * 4 + 2][k], wk, a2);
        a3 = fmaf(xs[wave * 4 + 3][k], wk, a3);
    }
    if (r0 + 0 < N) h2[(size_t)(r0 + 0) * DOUT + lane] = a0;
    if (r0 + 1 < N) h2[(size_t)(r0 + 1) * DOUT + lane] = a1;
    if (r0 + 2 < N) h2[(size_t)(r0 + 2) * DOUT + lane] = a2;
    if (r0 + 3 < N) h2[(size_t)(r0 + 3) * DOUT + lane] = a3;
}

// ---------------- gather layer 2 + fused bias/self-loop; writes d_out ----------------
// one wave per node; lane owns dim `lane`
__global__ __launch_bounds__(256) void k_gather2(const int* __restrict__ rowptr,
                                                 const int* __restrict__ srcs,
                                                 const float* __restrict__ dinv,
                                                 const float* __restrict__ h2,
                                                 const float* __restrict__ b2,
                                                 float* __restrict__ out, int N) {
    int w = (blockIdx.x * 256 + threadIdx.x) >> 6;
    int lane = threadIdx.x & 63;
    if (w >= N) return;
    int beg = rowptr[w], end = rowptr[w + 1];
    float a = 0.f;
    int e = beg;
    for (; e + 1 < end; e += 2) {
        int s0 = srcs[e], s1 = srcs[e + 1];
        float d0 = dinv[s0], d1 = dinv[s1];
        float v0 = h2[(size_t)s0 * DOUT + lane];
        float v1 = h2[(size_t)s1 * DOUT + lane];
        a = fmaf(d0, v0, a); a = fmaf(d1, v1, a);
    }
    if (e < end) {
        int s0 = srcs[e];
        a = fmaf(dinv[s0], h2[(size_t)s0 * DOUT + lane], a);
    }
    float di = dinv[w], self = di * di;
    out[(size_t)w * DOUT + lane] = fmaf(di, a, fmaf(self, h2[(size_t)w * DOUT + lane], b2[lane]));
}

extern "C" void kernel_launch(void* const* d_in, const int* in_sizes, int n_in,
                              void* d_out, int out_size, void* d_ws, size_t ws_size,
                              hipStream_t stream) {
    const float* x  = (const float*)d_in[0];
    const int*   ei = (const int*)d_in[1];
    const float* W1 = (const float*)d_in[2];
    const float* b1 = (const float*)d_in[3];
    const float* W2 = (const float*)d_in[4];
    const float* b2 = (const float*)d_in[5];

    const int N = in_sizes[0] / DIN;     // 100000
    const int E = in_sizes[1] / 2;       // 1600000
    const int* rows = ei;                // sources
    const int* cols = ei + E;            // destinations

    // workspace (~110.5 MB)
    char* p = (char*)d_ws;
    float* h1     = (float*)p;  p += (size_t)N * DHID * 4;  // 51.2 MB (reused as h2)
    float* hact   = (float*)p;  p += (size_t)N * DHID * 4;  // 51.2 MB
    int*   srcs   = (int*)p;    p += (size_t)E * 4;         // 6.4 MB
    int*   rowptr = (int*)p;    p += (size_t)(N + 1) * 4;
    int*   cursor = (int*)p;    p += (size_t)N * 4;
    int*   deg    = (int*)p;    p += (size_t)N * 4;
    float* dinv   = (float*)p;  p += (size_t)N * 4;
    int*   partials = (int*)p;  p += 256 * 4;
    float* h2 = h1;  // h1 dead after k_gather1

    const int nblk = (N + SCAN_CHUNK - 1) / SCAN_CHUNK;  // 98

    // CSR build
    hipMemsetAsync(deg, 0, (size_t)N * 4, stream);
    k_deg<<<(E + 255) / 256, 256, 0, stream>>>(cols, deg, E);
    k_partial<<<nblk, 256, 0, stream>>>(deg, partials, N);
    k_scan<<<nblk, 256, 0, stream>>>(deg, partials, rowptr, N, nblk);
    k_dinv<<<(N + 255) / 256, 256, 0, stream>>>(deg, dinv, N);
    hipMemcpyAsync(cursor, rowptr, (size_t)N * 4, hipMemcpyDeviceToDevice, stream);
    k_bucket<<<(E + 255) / 256, 256, 0, stream>>>(rows, cols, cursor, srcs, E);

    // layer 1
    k_gemm1<<<(N + 15) / 16, 256, 0, stream>>>(x, W1, h1, N);
    k_gather1<<<(N + 3) / 4, 256, 0, stream>>>(rowptr, srcs, dinv, h1, b1, hact, N);

    // layer 2
    k_gemm2<<<(N + 15) / 16, 256, 0, stream>>>(hact, W2, h2, N);
    k_gather2<<<(N + 3) / 4, 256, 0, stream>>>(rowptr, srcs, dinv, h2, b2, (float*)d_out, N);
}

// Round 4
// 625.349 us; speedup vs baseline: 2.0982x; 1.0242x over previous
//
#include <hip/hip_runtime.h>

// GCN 2-layer forward, f32 wire, bf16-compressed gather tables.
// out[i] = di * sum_{(j,i) in E} dj*h[j] + di^2*h[i] + b   (di = rsqrt(deg_i+1))
// Gathers are L2-miss bound: FETCH ~= 8 XCDs x table size. Storing h1/h2 as
// bf16 halves the table, accumulation stays f32.

#define DIN 128
#define DHID 128
#define DOUT 64
#define SCAN_CHUNK 1024

__device__ __forceinline__ float bf2f(unsigned int u16) {
    return __uint_as_float(u16 << 16);
}
__device__ __forceinline__ unsigned short f2bf(float f) {
    unsigned int u = __float_as_uint(f);
    u += 0x7fffu + ((u >> 16) & 1u);   // RNE
    return (unsigned short)(u >> 16);
}
__device__ __forceinline__ unsigned int pack2(float a, float b) {
    return (unsigned int)f2bf(a) | ((unsigned int)f2bf(b) << 16);
}

// ---------------- degree histogram ----------------
__global__ void k_deg(const int* __restrict__ cols, int* __restrict__ deg, int E) {
    int i = blockIdx.x * blockDim.x + threadIdx.x;
    if (i < E) atomicAdd(&deg[cols[i]], 1);
}

__global__ void k_dinv(const int* __restrict__ deg, float* __restrict__ dinv, int N) {
    int i = blockIdx.x * blockDim.x + threadIdx.x;
    if (i < N) dinv[i] = rsqrtf((float)(deg[i] + 1));
}

// ---------------- exclusive scan (two-kernel, 1024 elems/block) ----------------
__global__ __launch_bounds__(256) void k_partial(const int* __restrict__ cnt,
                                                 int* __restrict__ partials, int N) {
    __shared__ int s[256];
    int b = blockIdx.x, t = threadIdx.x;
    int base = b * SCAN_CHUNK + t * 4;
    int sum = 0;
#pragma unroll
    for (int i = 0; i < 4; ++i) { int idx = base + i; if (idx < N) sum += cnt[idx]; }
    s[t] = sum; __syncthreads();
    for (int off = 128; off > 0; off >>= 1) { if (t < off) s[t] += s[t + off]; __syncthreads(); }
    if (t == 0) partials[b] = s[0];
}

// assumes nblk <= 256
__global__ __launch_bounds__(256) void k_scan(const int* __restrict__ cnt,
                                              const int* __restrict__ partials,
                                              int* __restrict__ rowptr, int N, int nblk) {
    __shared__ int s[256];
    int b = blockIdx.x, t = threadIdx.x;
    s[t] = (t < b && t < nblk) ? partials[t] : 0;
    __syncthreads();
    for (int off = 128; off > 0; off >>= 1) { if (t < off) s[t] += s[t + off]; __syncthreads(); }
    int blockOff = s[0];
    __syncthreads();
    int base = b * SCAN_CHUNK + t * 4;
    int v[4]; int sum = 0;
#pragma unroll
    for (int i = 0; i < 4; ++i) { int idx = base + i; v[i] = (idx < N) ? cnt[idx] : 0; sum += v[i]; }
    s[t] = sum; __syncthreads();
    for (int off = 1; off < 256; off <<= 1) {
        int xv = s[t]; if (t >= off) xv += s[t - off];
        __syncthreads(); s[t] = xv; __syncthreads();
    }
    int run = blockOff + (t == 0 ? 0 : s[t - 1]);
#pragma unroll
    for (int i = 0; i < 4; ++i) {
        int idx = base + i;
        if (idx < N) rowptr[idx] = run;
        run += v[i];
        if (idx == N - 1) rowptr[N] = run;   // == E
    }
}

// ---------------- bucket edges into CSR order ----------------
__global__ void k_bucket(const int* __restrict__ rows, const int* __restrict__ cols,
                         int* __restrict__ cursor, int* __restrict__ srcs, int E) {
    int e = blockIdx.x * blockDim.x + threadIdx.x;
    if (e >= E) return;
    int c = cols[e];
    int pos = atomicAdd(&cursor[c], 1);
    srcs[pos] = rows[e];
}

// ---------------- GEMM1: h1[N,128] = x @ W1, stored bf16-packed ----------------
// lane owns cols {2l, 2l+1}; wave does 4 rows; block 16 rows.
__global__ __launch_bounds__(256) void k_gemm1(const float* __restrict__ x,
                                               const float* __restrict__ W,
                                               unsigned int* __restrict__ h1u, int N) {
    __shared__ float xs[16][DIN];
    int t = threadIdx.x;
    int rowBase = blockIdx.x * 16;
    {
        int li = t * 8;
        int lr = li >> 7, lc = li & 127;
        int gr = rowBase + lr;
        if (gr < N) {
            const float4* src = (const float4*)(x + (size_t)gr * DIN + lc);
            float4 a = src[0], b = src[1];
            *(float4*)&xs[lr][lc] = a;
            *(float4*)&xs[lr][lc + 4] = b;
        }
    }
    __syncthreads();
    int wave = t >> 6, lane = t & 63;
    int r0 = rowBase + wave * 4;
    float acc[4][2] = {{0.f,0.f},{0.f,0.f},{0.f,0.f},{0.f,0.f}};
#pragma unroll 4
    for (int k = 0; k < DIN; ++k) {
        float2 wv = *(const float2*)(W + k * DHID + 2 * lane);
#pragma unroll
        for (int r = 0; r < 4; ++r) {
            float xv = xs[wave * 4 + r][k];
            acc[r][0] = fmaf(xv, wv.x, acc[r][0]);
            acc[r][1] = fmaf(xv, wv.y, acc[r][1]);
        }
    }
#pragma unroll
    for (int r = 0; r < 4; ++r) {
        int gr = r0 + r;
        if (gr < N) h1u[(size_t)gr * 64 + lane] = pack2(acc[r][0], acc[r][1]);
    }
}

// ---------------- gather layer 1 + fused bias/self-loop/relu ----------------
// one wave per dst node; lane owns dims {2l, 2l+1} (one packed uint per row)
__global__ __launch_bounds__(256) void k_gather1(const int* __restrict__ rowptr,
                                                 const int* __restrict__ srcs,
                                                 const float* __restrict__ dinv,
                                                 const unsigned int* __restrict__ h1u,
                                                 const float* __restrict__ b1,
                                                 float* __restrict__ hact, int N) {
    int w = (blockIdx.x * 256 + threadIdx.x) >> 6;
    int lane = threadIdx.x & 63;
    if (w >= N) return;
    int beg = rowptr[w], end = rowptr[w + 1];
    float a0 = 0.f, a1 = 0.f;
    int e = beg;
    for (; e + 1 < end; e += 2) {
        int s0 = srcs[e], s1 = srcs[e + 1];
        float d0 = dinv[s0], d1 = dinv[s1];
        unsigned int v0 = h1u[(size_t)s0 * 64 + lane];
        unsigned int v1 = h1u[(size_t)s1 * 64 + lane];
        a0 = fmaf(d0, bf2f(v0 & 0xffffu), a0); a1 = fmaf(d0, bf2f(v0 >> 16), a1);
        a0 = fmaf(d1, bf2f(v1 & 0xffffu), a0); a1 = fmaf(d1, bf2f(v1 >> 16), a1);
    }
    if (e < end) {
        int s0 = srcs[e];
        float d0 = dinv[s0];
        unsigned int v0 = h1u[(size_t)s0 * 64 + lane];
        a0 = fmaf(d0, bf2f(v0 & 0xffffu), a0); a1 = fmaf(d0, bf2f(v0 >> 16), a1);
    }
    float di = dinv[w], self = di * di;
    unsigned int hv = h1u[(size_t)w * 64 + lane];
    float2 bv = *(const float2*)(b1 + 2 * lane);
    float r0 = fmaf(di, a0, fmaf(self, bf2f(hv & 0xffffu), bv.x));
    float r1 = fmaf(di, a1, fmaf(self, bf2f(hv >> 16), bv.y));
    float2 out; out.x = fmaxf(r0, 0.f); out.y = fmaxf(r1, 0.f);
    *(float2*)(hact + (size_t)w * DHID + 2 * lane) = out;
}

// ---------------- GEMM2: h2[N,64] = hact @ W2, stored bf16 ----------------
__global__ __launch_bounds__(256) void k_gemm2(const float* __restrict__ hact,
                                               const float* __restrict__ W,
                                               unsigned short* __restrict__ h2u, int N) {
    __shared__ float xs[16][DHID];
    int t = threadIdx.x;
    int rowBase = blockIdx.x * 16;
    {
        int li = t * 8;
        int lr = li >> 7, lc = li & 127;
        int gr = rowBase + lr;
        if (gr < N) {
            const float4* src = (const float4*)(hact + (size_t)gr * DHID + lc);
            float4 a = src[0], b = src[1];
            *(float4*)&xs[lr][lc] = a;
            *(float4*)&xs[lr][lc + 4] = b;
        }
    }
    __syncthreads();
    int wave = t >> 6, lane = t & 63;
    int r0 = rowBase + wave * 4;
    float a0 = 0.f, a1 = 0.f, a2 = 0.f, a3 = 0.f;
#pragma unroll 4
    for (int k = 0; k < DHID; ++k) {
        float wk = W[k * DOUT + lane];
        a0 = fmaf(xs[wave * 4 + 0][k], wk, a0);
        a1 = fmaf(xs[wave * 4 + 1][k], wk, a1);
        a2 = fmaf(xs[wave * 4 + 2][k], wk, a2);
        a3 = fmaf(xs[wave * 4 + 3][k], wk, a3);
    }
    if (r0 + 0 < N) h2u[(size_t)(r0 + 0) * DOUT + lane] = f2bf(a0);
    if (r0 + 1 < N) h2u[(size_t)(r0 + 1) * DOUT + lane] = f2bf(a1);
    if (r0 + 2 < N) h2u[(size_t)(r0 + 2) * DOUT + lane] = f2bf(a2);
    if (r0 + 3 < N) h2u[(size_t)(r0 + 3) * DOUT + lane] = f2bf(a3);
}

// ---------------- gather layer 2 + fused bias/self-loop; writes d_out ----------------
__global__ __launch_bounds__(256) void k_gather2(const int* __restrict__ rowptr,
                                                 const int* __restrict__ srcs,
                                                 const float* __restrict__ dinv,
                                                 const unsigned short* __restrict__ h2u,
                                                 const float* __restrict__ b2,
                                                 float* __restrict__ out, int N) {
    int w = (blockIdx.x * 256 + threadIdx.x) >> 6;
    int lane = threadIdx.x & 63;
    if (w >= N) return;
    int beg = rowptr[w], end = rowptr[w + 1];
    float a = 0.f;
    int e = beg;
    for (; e + 1 < end; e += 2) {
        int s0 = srcs[e], s1 = srcs[e + 1];
        float d0 = dinv[s0], d1 = dinv[s1];
        float v0 = bf2f((unsigned int)h2u[(size_t)s0 * DOUT + lane]);
        float v1 = bf2f((unsigned int)h2u[(size_t)s1 * DOUT + lane]);
        a = fmaf(d0, v0, a); a = fmaf(d1, v1, a);
    }
    if (e < end) {
        int s0 = srcs[e];
        a = fmaf(dinv[s0], bf2f((unsigned int)h2u[(size_t)s0 * DOUT + lane]), a);
    }
    float di = dinv[w], self = di * di;
    float hv = bf2f((unsigned int)h2u[(size_t)w * DOUT + lane]);
    out[(size_t)w * DOUT + lane] = fmaf(di, a, fmaf(self, hv, b2[lane]));
}

extern "C" void kernel_launch(void* const* d_in, const int* in_sizes, int n_in,
                              void* d_out, int out_size, void* d_ws, size_t ws_size,
                              hipStream_t stream) {
    const float* x  = (const float*)d_in[0];
    const int*   ei = (const int*)d_in[1];
    const float* W1 = (const float*)d_in[2];
    const float* b1 = (const float*)d_in[3];
    const float* W2 = (const float*)d_in[4];
    const float* b2 = (const float*)d_in[5];

    const int N = in_sizes[0] / DIN;     // 100000
    const int E = in_sizes[1] / 2;       // 1600000
    const int* rows = ei;                // sources
    const int* cols = ei + E;            // destinations

    // workspace (~85 MB)
    char* p = (char*)d_ws;
    unsigned int* h1u = (unsigned int*)p;  p += (size_t)N * 64 * 4;   // 25.6 MB (bf16 pairs)
    float* hact   = (float*)p;  p += (size_t)N * DHID * 4;            // 51.2 MB
    int*   srcs   = (int*)p;    p += (size_t)E * 4;                   // 6.4 MB
    int*   rowptr = (int*)p;    p += (size_t)(N + 1) * 4;
    int*   cursor = (int*)p;    p += (size_t)N * 4;
    int*   deg    = (int*)p;    p += (size_t)N * 4;
    float* dinv   = (float*)p;  p += (size_t)N * 4;
    int*   partials = (int*)p;  p += 256 * 4;
    unsigned short* h2u = (unsigned short*)h1u;  // alias: h1 dead after k_gather1

    const int nblk = (N + SCAN_CHUNK - 1) / SCAN_CHUNK;  // 98

    // CSR build
    hipMemsetAsync(deg, 0, (size_t)N * 4, stream);
    k_deg<<<(E + 255) / 256, 256, 0, stream>>>(cols, deg, E);
    k_partial<<<nblk, 256, 0, stream>>>(deg, partials, N);
    k_scan<<<nblk, 256, 0, stream>>>(deg, partials, rowptr, N, nblk);
    k_dinv<<<(N + 255) / 256, 256, 0, stream>>>(deg, dinv, N);
    hipMemcpyAsync(cursor, rowptr, (size_t)N * 4, hipMemcpyDeviceToDevice, stream);
    k_bucket<<<(E + 255) / 256, 256, 0, stream>>>(rows, cols, cursor, srcs, E);

    // layer 1
    k_gemm1<<<(N + 15) / 16, 256, 0, stream>>>(x, W1, h1u, N);
    k_gather1<<<(N + 3) / 4, 256, 0, stream>>>(rowptr, srcs, dinv, h1u, b1, hact, N);

    // layer 2 (h2u aliases h1u; h1 consumed by k_gather1)
    k_gemm2<<<(N + 15) / 16, 256, 0, stream>>>(hact, W2, h2u, N);
    k_gather2<<<(N + 3) / 4, 256, 0, stream>>>(rowptr, srcs, dinv, h2u, b2, (float*)d_out, N);
}

// Round 5
// 514.085 us; speedup vs baseline: 2.5523x; 1.2164x over previous
//
#include <hip/hip_runtime.h>

// GCN 2-layer forward, f32 wire, bf16-compressed gather tables, padded-ELL
// adjacency built in ONE destination-range-partitioned pass (no CSR scan).
// out[i] = di * sum_{(j,i) in E} dj*h[j] + di^2*h[i] + b   (di = rsqrt(deg_i+1))

#define DIN 128
#define DHID 128
#define DOUT 64
#define ELLW 64     // max in-degree supported (Poisson(16): P(>=64) ~ 1e-22)
#define GPART 8     // destination-range groups (one per XCD, blockIdx&7 heuristic)
#define BPG 256     // blocks per group

__device__ __forceinline__ float bf2f(unsigned int u16) {
    return __uint_as_float(u16 << 16);
}
__device__ __forceinline__ unsigned short f2bf(float f) {
    unsigned int u = __float_as_uint(f);
    u += 0x7fffu + ((u >> 16) & 1u);   // RNE
    return (unsigned short)(u >> 16);
}
__device__ __forceinline__ unsigned int pack2(float a, float b) {
    return (unsigned int)f2bf(a) | ((unsigned int)f2bf(b) << 16);
}

// ---------------- fused degree + ELL bucket, dst-range partitioned ----------------
// group g handles dsts in [g*R, (g+1)*R): its ELL slice (~3.2MB) stays in one L2.
__global__ __launch_bounds__(256) void k_fill(const int* __restrict__ rows,
                                              const int* __restrict__ cols,
                                              int* __restrict__ deg,
                                              int* __restrict__ ell,
                                              int E, int perBlock, int R) {
    int g  = blockIdx.x & (GPART - 1);
    int cb = blockIdx.x >> 3;
    int lo = g * R, hi = lo + R;
    int eBeg = cb * perBlock;
    int eEnd = eBeg + perBlock; if (eEnd > E) eEnd = E;
    for (int e = eBeg + threadIdx.x; e < eEnd; e += 256) {
        int c = cols[e];
        if (c >= lo && c < hi) {
            int r = rows[e];
            int k = atomicAdd(&deg[c], 1);
            if (k < ELLW) ell[(size_t)c * ELLW + k] = r;
        }
    }
}

__global__ void k_dinv(const int* __restrict__ deg, float* __restrict__ dinv, int N) {
    int i = blockIdx.x * blockDim.x + threadIdx.x;
    if (i < N) dinv[i] = rsqrtf((float)(deg[i] + 1));
}

// ---------------- GEMM1: h1[N,128] = x @ W1, stored bf16-packed ----------------
__global__ __launch_bounds__(256) void k_gemm1(const float* __restrict__ x,
                                               const float* __restrict__ W,
                                               unsigned int* __restrict__ h1u, int N) {
    __shared__ float xs[16][DIN];
    int t = threadIdx.x;
    int rowBase = blockIdx.x * 16;
    {
        int li = t * 8;
        int lr = li >> 7, lc = li & 127;
        int gr = rowBase + lr;
        if (gr < N) {
            const float4* src = (const float4*)(x + (size_t)gr * DIN + lc);
            float4 a = src[0], b = src[1];
            *(float4*)&xs[lr][lc] = a;
            *(float4*)&xs[lr][lc + 4] = b;
        }
    }
    __syncthreads();
    int wave = t >> 6, lane = t & 63;
    int r0 = rowBase + wave * 4;
    float acc[4][2] = {{0.f,0.f},{0.f,0.f},{0.f,0.f},{0.f,0.f}};
#pragma unroll 4
    for (int k = 0; k < DIN; ++k) {
        float2 wv = *(const float2*)(W + k * DHID + 2 * lane);
#pragma unroll
        for (int r = 0; r < 4; ++r) {
            float xv = xs[wave * 4 + r][k];
            acc[r][0] = fmaf(xv, wv.x, acc[r][0]);
            acc[r][1] = fmaf(xv, wv.y, acc[r][1]);
        }
    }
#pragma unroll
    for (int r = 0; r < 4; ++r) {
        int gr = r0 + r;
        if (gr < N) h1u[(size_t)gr * 64 + lane] = pack2(acc[r][0], acc[r][1]);
    }
}

// ---------------- gather layer 1 + fused bias/self-loop/relu ----------------
// one wave per dst node; lane owns dims {2l, 2l+1} (one packed uint per row)
__global__ __launch_bounds__(256) void k_gather1(const int* __restrict__ deg,
                                                 const int* __restrict__ ell,
                                                 const float* __restrict__ dinv,
                                                 const unsigned int* __restrict__ h1u,
                                                 const float* __restrict__ b1,
                                                 float* __restrict__ hact, int N) {
    int w = (blockIdx.x * 256 + threadIdx.x) >> 6;
    int lane = threadIdx.x & 63;
    if (w >= N) return;
    int d = deg[w];
    const int* el = ell + (size_t)w * ELLW;
    float a0 = 0.f, a1 = 0.f;
    int e = 0;
    for (; e + 1 < d; e += 2) {
        int s0 = el[e], s1 = el[e + 1];
        float d0 = dinv[s0], d1 = dinv[s1];
        unsigned int v0 = h1u[(size_t)s0 * 64 + lane];
        unsigned int v1 = h1u[(size_t)s1 * 64 + lane];
        a0 = fmaf(d0, bf2f(v0 & 0xffffu), a0); a1 = fmaf(d0, bf2f(v0 >> 16), a1);
        a0 = fmaf(d1, bf2f(v1 & 0xffffu), a0); a1 = fmaf(d1, bf2f(v1 >> 16), a1);
    }
    if (e < d) {
        int s0 = el[e];
        float d0 = dinv[s0];
        unsigned int v0 = h1u[(size_t)s0 * 64 + lane];
        a0 = fmaf(d0, bf2f(v0 & 0xffffu), a0); a1 = fmaf(d0, bf2f(v0 >> 16), a1);
    }
    float di = dinv[w], self = di * di;
    unsigned int hv = h1u[(size_t)w * 64 + lane];
    float2 bv = *(const float2*)(b1 + 2 * lane);
    float r0 = fmaf(di, a0, fmaf(self, bf2f(hv & 0xffffu), bv.x));
    float r1 = fmaf(di, a1, fmaf(self, bf2f(hv >> 16), bv.y));
    float2 out; out.x = fmaxf(r0, 0.f); out.y = fmaxf(r1, 0.f);
    *(float2*)(hact + (size_t)w * DHID + 2 * lane) = out;
}

// ---------------- GEMM2: h2[N,64] = hact @ W2, stored bf16 ----------------
__global__ __launch_bounds__(256) void k_gemm2(const float* __restrict__ hact,
                                               const float* __restrict__ W,
                                               unsigned short* __restrict__ h2u, int N) {
    __shared__ float xs[16][DHID];
    int t = threadIdx.x;
    int rowBase = blockIdx.x * 16;
    {
        int li = t * 8;
        int lr = li >> 7, lc = li & 127;
        int gr = rowBase + lr;
        if (gr < N) {
            const float4* src = (const float4*)(hact + (size_t)gr * DHID + lc);
            float4 a = src[0], b = src[1];
            *(float4*)&xs[lr][lc] = a;
            *(float4*)&xs[lr][lc + 4] = b;
        }
    }
    __syncthreads();
    int wave = t >> 6, lane = t & 63;
    int r0 = rowBase + wave * 4;
    float a0 = 0.f, a1 = 0.f, a2 = 0.f, a3 = 0.f;
#pragma unroll 4
    for (int k = 0; k < DHID; ++k) {
        float wk = W[k * DOUT + lane];
        a0 = fmaf(xs[wave * 4 + 0][k], wk, a0);
        a1 = fmaf(xs[wave * 4 + 1][k], wk, a1);
        a2 = fmaf(xs[wave * 4 + 2][k], wk, a2);
        a3 = fmaf(xs[wave * 4 + 3][k], wk, a3);
    }
    if (r0 + 0 < N) h2u[(size_t)(r0 + 0) * DOUT + lane] = f2bf(a0);
    if (r0 + 1 < N) h2u[(size_t)(r0 + 1) * DOUT + lane] = f2bf(a1);
    if (r0 + 2 < N) h2u[(size_t)(r0 + 2) * DOUT + lane] = f2bf(a2);
    if (r0 + 3 < N) h2u[(size_t)(r0 + 3) * DOUT + lane] = f2bf(a3);
}

// ---------------- gather layer 2 + fused bias/self-loop; writes d_out ----------------
__global__ __launch_bounds__(256) void k_gather2(const int* __restrict__ deg,
                                                 const int* __restrict__ ell,
                                                 const float* __restrict__ dinv,
                                                 const unsigned short* __restrict__ h2u,
                                                 const float* __restrict__ b2,
                                                 float* __restrict__ out, int N) {
    int w = (blockIdx.x * 256 + threadIdx.x) >> 6;
    int lane = threadIdx.x & 63;
    if (w >= N) return;
    int d = deg[w];
    const int* el = ell + (size_t)w * ELLW;
    float a = 0.f;
    int e = 0;
    for (; e + 1 < d; e += 2) {
        int s0 = el[e], s1 = el[e + 1];
        float d0 = dinv[s0], d1 = dinv[s1];
        float v0 = bf2f((unsigned int)h2u[(size_t)s0 * DOUT + lane]);
        float v1 = bf2f((unsigned int)h2u[(size_t)s1 * DOUT + lane]);
        a = fmaf(d0, v0, a); a = fmaf(d1, v1, a);
    }
    if (e < d) {
        int s0 = el[e];
        a = fmaf(dinv[s0], bf2f((unsigned int)h2u[(size_t)s0 * DOUT + lane]), a);
    }
    float di = dinv[w], self = di * di;
    float hv = bf2f((unsigned int)h2u[(size_t)w * DOUT + lane]);
    out[(size_t)w * DOUT + lane] = fmaf(di, a, fmaf(self, hv, b2[lane]));
}

extern "C" void kernel_launch(void* const* d_in, const int* in_sizes, int n_in,
                              void* d_out, int out_size, void* d_ws, size_t ws_size,
                              hipStream_t stream) {
    const float* x  = (const float*)d_in[0];
    const int*   ei = (const int*)d_in[1];
    const float* W1 = (const float*)d_in[2];
    const float* b1 = (const float*)d_in[3];
    const float* W2 = (const float*)d_in[4];
    const float* b2 = (const float*)d_in[5];

    const int N = in_sizes[0] / DIN;     // 100000
    const int E = in_sizes[1] / 2;       // 1600000
    const int* rows = ei;                // sources
    const int* cols = ei + E;            // destinations

    // workspace (~103.2 MB)
    char* p = (char*)d_ws;
    int*   ell  = (int*)p;          p += (size_t)N * ELLW * 4;   // 25.6 MB
    unsigned int* h1u = (unsigned int*)p;  p += (size_t)N * 64 * 4;  // 25.6 MB (bf16 pairs)
    float* hact = (float*)p;        p += (size_t)N * DHID * 4;   // 51.2 MB
    int*   deg  = (int*)p;          p += (size_t)N * 4;
    float* dinv = (float*)p;        p += (size_t)N * 4;
    unsigned short* h2u = (unsigned short*)h1u;  // alias: h1 dead after k_gather1

    const int R = (N + GPART - 1) / GPART;          // 12500 dsts per group
    const int perBlock = (E + BPG - 1) / BPG;       // 6250 edges per block-chunk

    // adjacency build (single pass)
    hipMemsetAsync(deg, 0, (size_t)N * 4, stream);
    k_fill<<<GPART * BPG, 256, 0, stream>>>(rows, cols, deg, ell, E, perBlock, R);
    k_dinv<<<(N + 255) / 256, 256, 0, stream>>>(deg, dinv, N);

    // layer 1
    k_gemm1<<<(N + 15) / 16, 256, 0, stream>>>(x, W1, h1u, N);
    k_gather1<<<(N + 3) / 4, 256, 0, stream>>>(deg, ell, dinv, h1u, b1, hact, N);

    // layer 2 (h2u aliases h1u; h1 consumed by k_gather1)
    k_gemm2<<<(N + 15) / 16, 256, 0, stream>>>(hact, W2, h2u, N);
    k_gather2<<<(N + 3) / 4, 256, 0, stream>>>(deg, ell, dinv, h2u, b2, (float*)d_out, N);
}

// Round 6
// 399.564 us; speedup vs baseline: 3.2838x; 1.2866x over previous
//
#include <hip/hip_runtime.h>

// GCN 2-layer forward. f32 wire; bf16 MFMA GEMMs (f32 accumulate); bf16 gather
// tables; padded-ELL adjacency built in one dst-range-partitioned pass.
// out[i] = di * sum_{(j,i) in E} dj*h[j] + di^2*h[i] + b   (di = rsqrt(deg_i+1))

#define DIN 128
#define DHID 128
#define DOUT 64
#define ELLW 64     // max in-degree (Poisson(16): P(>=64) ~ 1e-22)
#define GPART 8
#define BPG 256

typedef __attribute__((ext_vector_type(4))) float f32x4;
typedef __attribute__((ext_vector_type(8))) short bf16x8;

__device__ __forceinline__ float bf2f(unsigned int u16) {
    return __uint_as_float(u16 << 16);
}
__device__ __forceinline__ unsigned short f2bf(float f) {
    unsigned int u = __float_as_uint(f);
    u += 0x7fffu + ((u >> 16) & 1u);   // RNE
    return (unsigned short)(u >> 16);
}
__device__ __forceinline__ unsigned int pack2(float a, float b) {
    return (unsigned int)f2bf(a) | ((unsigned int)f2bf(b) << 16);
}

// ---------------- fused degree + ELL bucket, dst-range partitioned ----------------
__global__ __launch_bounds__(256) void k_fill(const int* __restrict__ rows,
                                              const int* __restrict__ cols,
                                              int* __restrict__ deg,
                                              int* __restrict__ ell,
                                              int E, int perBlock, int R) {
    int g  = blockIdx.x & (GPART - 1);
    int cb = blockIdx.x >> 3;
    int lo = g * R, hi = lo + R;
    int eBeg = cb * perBlock;
    int eEnd = eBeg + perBlock; if (eEnd > E) eEnd = E;
    for (int e = eBeg + threadIdx.x; e < eEnd; e += 256) {
        int c = cols[e];
        if (c >= lo && c < hi) {
            int r = rows[e];
            int k = atomicAdd(&deg[c], 1);
            if (k < ELLW) ell[(size_t)c * ELLW + k] = r;
        }
    }
}

__global__ void k_dinv(const int* __restrict__ deg, float* __restrict__ dinv, int N) {
    int i = blockIdx.x * blockDim.x + threadIdx.x;
    if (i < N) dinv[i] = rsqrtf((float)(deg[i] + 1));
}

// ---------------- pack W1/W2 into MFMA B-fragment order, bf16 ----------------
// slot id = t*256 + s*64 + lane; element j: B[k = s*32 + (lane>>4)*8 + j][n = t*16 + (lane&15)]
__global__ __launch_bounds__(256) void k_packW(const float* __restrict__ W1,
                                               const float* __restrict__ W2,
                                               unsigned short* __restrict__ w1p,
                                               unsigned short* __restrict__ w2p) {
    int id = blockIdx.x * 256 + threadIdx.x;
    if (id < 2048) {                     // W1: 8 n-tiles x 4 k-steps x 64 lanes
        int lane = id & 63, s = (id >> 6) & 3, t = id >> 8;
        int n = t * 16 + (lane & 15);
        int k0 = s * 32 + (lane >> 4) * 8;
#pragma unroll
        for (int j = 0; j < 8; ++j)
            w1p[(size_t)id * 8 + j] = f2bf(W1[(k0 + j) * DHID + n]);
    } else if (id < 3072) {              // W2: 4 n-tiles x 4 k-steps x 64 lanes
        int id2 = id - 2048;
        int lane = id2 & 63, s = (id2 >> 6) & 3, t = id2 >> 8;
        int n = t * 16 + (lane & 15);
        int k0 = s * 32 + (lane >> 4) * 8;
#pragma unroll
        for (int j = 0; j < 8; ++j)
            w2p[(size_t)id2 * 8 + j] = f2bf(W2[(k0 + j) * DOUT + n]);
    }
}

// ---------------- GEMM1 (MFMA): h1b[N,128] bf16 = bf16(x) @ bf16(W1) ----------------
// wave: 16 rows x 128 cols; A-frags converted from f32 x inline.
__global__ __launch_bounds__(256) void k_gemm1(const float* __restrict__ x,
                                               const unsigned short* __restrict__ w1p,
                                               unsigned short* __restrict__ h1b, int N) {
    int wave = threadIdx.x >> 6, lane = threadIdx.x & 63;
    int quad = lane >> 4, qr = lane & 15;
    int rowBase = blockIdx.x * 64 + wave * 16;
    int arow = rowBase + qr;
    bool rowOK = arow < N;
    f32x4 acc[8] = {};
#pragma unroll
    for (int s = 0; s < 4; ++s) {
        bf16x8 a = {};
        if (rowOK) {
            const float* ap = x + (size_t)arow * DIN + s * 32 + quad * 8;
            float4 lo = *(const float4*)ap;
            float4 hi = *(const float4*)(ap + 4);
            a[0] = (short)f2bf(lo.x); a[1] = (short)f2bf(lo.y);
            a[2] = (short)f2bf(lo.z); a[3] = (short)f2bf(lo.w);
            a[4] = (short)f2bf(hi.x); a[5] = (short)f2bf(hi.y);
            a[6] = (short)f2bf(hi.z); a[7] = (short)f2bf(hi.w);
        }
#pragma unroll
        for (int t = 0; t < 8; ++t) {
            bf16x8 b = *(const bf16x8*)(w1p + ((size_t)(t * 4 + s) * 64 + lane) * 8);
            acc[t] = __builtin_amdgcn_mfma_f32_16x16x32_bf16(a, b, acc[t], 0, 0, 0);
        }
    }
    // D[row = quad*4 + i][col = t*16 + qr]
#pragma unroll
    for (int t = 0; t < 8; ++t)
#pragma unroll
        for (int i = 0; i < 4; ++i) {
            int r = rowBase + quad * 4 + i;
            if (r < N) h1b[(size_t)r * DHID + t * 16 + qr] = f2bf(acc[t][i]);
        }
}

// ---------------- gather layer 1 + fused bias/self-loop/relu -> bf16 hact ----------------
__global__ __launch_bounds__(256) void k_gather1(const int* __restrict__ deg,
                                                 const int* __restrict__ ell,
                                                 const float* __restrict__ dinv,
                                                 const unsigned int* __restrict__ h1u,
                                                 const float* __restrict__ b1,
                                                 unsigned int* __restrict__ hactu, int N) {
    int w = (blockIdx.x * 256 + threadIdx.x) >> 6;
    int lane = threadIdx.x & 63;
    if (w >= N) return;
    int d = deg[w];
    const int* el = ell + (size_t)w * ELLW;
    float a0 = 0.f, a1 = 0.f;
    int e = 0;
    for (; e + 1 < d; e += 2) {
        int s0 = el[e], s1 = el[e + 1];
        float d0 = dinv[s0], d1 = dinv[s1];
        unsigned int v0 = h1u[(size_t)s0 * 64 + lane];
        unsigned int v1 = h1u[(size_t)s1 * 64 + lane];
        a0 = fmaf(d0, bf2f(v0 & 0xffffu), a0); a1 = fmaf(d0, bf2f(v0 >> 16), a1);
        a0 = fmaf(d1, bf2f(v1 & 0xffffu), a0); a1 = fmaf(d1, bf2f(v1 >> 16), a1);
    }
    if (e < d) {
        int s0 = el[e];
        float d0 = dinv[s0];
        unsigned int v0 = h1u[(size_t)s0 * 64 + lane];
        a0 = fmaf(d0, bf2f(v0 & 0xffffu), a0); a1 = fmaf(d0, bf2f(v0 >> 16), a1);
    }
    float di = dinv[w], self = di * di;
    unsigned int hv = h1u[(size_t)w * 64 + lane];
    float2 bv = *(const float2*)(b1 + 2 * lane);
    float r0 = fmaf(di, a0, fmaf(self, bf2f(hv & 0xffffu), bv.x));
    float r1 = fmaf(di, a1, fmaf(self, bf2f(hv >> 16), bv.y));
    hactu[(size_t)w * 64 + lane] = pack2(fmaxf(r0, 0.f), fmaxf(r1, 0.f));
}

// ---------------- GEMM2 (MFMA): h2b[N,64] bf16 = hact(bf16) @ bf16(W2) ----------------
__global__ __launch_bounds__(256) void k_gemm2(const unsigned short* __restrict__ hactb,
                                               const unsigned short* __restrict__ w2p,
                                               unsigned short* __restrict__ h2b, int N) {
    int wave = threadIdx.x >> 6, lane = threadIdx.x & 63;
    int quad = lane >> 4, qr = lane & 15;
    int rowBase = blockIdx.x * 64 + wave * 16;
    int arow = rowBase + qr;
    bool rowOK = arow < N;
    f32x4 acc[4] = {};
#pragma unroll
    for (int s = 0; s < 4; ++s) {
        bf16x8 a = {};
        if (rowOK) a = *(const bf16x8*)(hactb + (size_t)arow * DHID + s * 32 + quad * 8);
#pragma unroll
        for (int t = 0; t < 4; ++t) {
            bf16x8 b = *(const bf16x8*)(w2p + ((size_t)(t * 4 + s) * 64 + lane) * 8);
            acc[t] = __builtin_amdgcn_mfma_f32_16x16x32_bf16(a, b, acc[t], 0, 0, 0);
        }
    }
#pragma unroll
    for (int t = 0; t < 4; ++t)
#pragma unroll
        for (int i = 0; i < 4; ++i) {
            int r = rowBase + quad * 4 + i;
            if (r < N) h2b[(size_t)r * DOUT + t * 16 + qr] = f2bf(acc[t][i]);
        }
}

// ---------------- gather layer 2 + fused bias/self-loop; writes d_out (f32) ----------------
__global__ __launch_bounds__(256) void k_gather2(const int* __restrict__ deg,
                                                 const int* __restrict__ ell,
                                                 const float* __restrict__ dinv,
                                                 const unsigned short* __restrict__ h2u,
                                                 const float* __restrict__ b2,
                                                 float* __restrict__ out, int N) {
    int w = (blockIdx.x * 256 + threadIdx.x) >> 6;
    int lane = threadIdx.x & 63;
    if (w >= N) return;
    int d = deg[w];
    const int* el = ell + (size_t)w * ELLW;
    float a = 0.f;
    int e = 0;
    for (; e + 1 < d; e += 2) {
        int s0 = el[e], s1 = el[e + 1];
        float d0 = dinv[s0], d1 = dinv[s1];
        float v0 = bf2f((unsigned int)h2u[(size_t)s0 * DOUT + lane]);
        float v1 = bf2f((unsigned int)h2u[(size_t)s1 * DOUT + lane]);
        a = fmaf(d0, v0, a); a = fmaf(d1, v1, a);
    }
    if (e < d) {
        int s0 = el[e];
        a = fmaf(dinv[s0], bf2f((unsigned int)h2u[(size_t)s0 * DOUT + lane]), a);
    }
    float di = dinv[w], self = di * di;
    float hv = bf2f((unsigned int)h2u[(size_t)w * DOUT + lane]);
    out[(size_t)w * DOUT + lane] = fmaf(di, a, fmaf(self, hv, b2[lane]));
}

extern "C" void kernel_launch(void* const* d_in, const int* in_sizes, int n_in,
                              void* d_out, int out_size, void* d_ws, size_t ws_size,
                              hipStream_t stream) {
    const float* x  = (const float*)d_in[0];
    const int*   ei = (const int*)d_in[1];
    const float* W1 = (const float*)d_in[2];
    const float* b1 = (const float*)d_in[3];
    const float* W2 = (const float*)d_in[4];
    const float* b2 = (const float*)d_in[5];

    const int N = in_sizes[0] / DIN;     // 100000
    const int E = in_sizes[1] / 2;       // 1600000
    const int* rows = ei;                // sources
    const int* cols = ei + E;            // destinations

    // workspace (~78 MB)
    char* p = (char*)d_ws;
    int*   ell  = (int*)p;                  p += (size_t)N * ELLW * 4;   // 25.6 MB
    unsigned short* h1b = (unsigned short*)p; p += (size_t)N * DHID * 2; // 25.6 MB
    unsigned short* hactb = (unsigned short*)p; p += (size_t)N * DHID * 2; // 25.6 MB
    unsigned short* w1p = (unsigned short*)p; p += (size_t)2048 * 8 * 2; // 32 KB
    unsigned short* w2p = (unsigned short*)p; p += (size_t)1024 * 8 * 2; // 16 KB
    int*   deg  = (int*)p;                  p += (size_t)N * 4;
    float* dinv = (float*)p;                p += (size_t)N * 4;
    unsigned short* h2b = h1b;   // alias: h1 dead after k_gather1 (needs 12.8 MB)

    const int R = (N + GPART - 1) / GPART;
    const int perBlock = (E + BPG - 1) / BPG;

    // adjacency build
    hipMemsetAsync(deg, 0, (size_t)N * 4, stream);
    k_fill<<<GPART * BPG, 256, 0, stream>>>(rows, cols, deg, ell, E, perBlock, R);
    k_dinv<<<(N + 255) / 256, 256, 0, stream>>>(deg, dinv, N);
    k_packW<<<12, 256, 0, stream>>>(W1, W2, w1p, w2p);

    // layer 1
    k_gemm1<<<(N + 63) / 64, 256, 0, stream>>>(x, w1p, h1b, N);
    k_gather1<<<(N + 3) / 4, 256, 0, stream>>>(deg, ell, dinv, (const unsigned int*)h1b,
                                               b1, (unsigned int*)hactb, N);

    // layer 2
    k_gemm2<<<(N + 63) / 64, 256, 0, stream>>>(hactb, w2p, h2b, N);
    k_gather2<<<(N + 3) / 4, 256, 0, stream>>>(deg, ell, dinv, h2b, b2, (float*)d_out, N);
}

// Round 7
// 321.518 us; speedup vs baseline: 4.0809x; 1.2427x over previous
//
#include <hip/hip_runtime.h>

// GCN 2-layer forward. f32 wire; bf16 MFMA GEMMs (f32 acc); bf16 gather tables;
// padded-ELL adjacency built in one dst-range-partitioned pass.
// Gather loop: ELL row + dinv preloaded per-lane, broadcast via __shfl, so the
// inner loop issues only independent 256B row gathers (4 in flight).

#define DIN 128
#define DHID 128
#define DOUT 64
#define ELLW 64     // max in-degree (Poisson(16): P(>=64) ~ 1e-22)
#define GPART 8
#define BPG 256

typedef __attribute__((ext_vector_type(4))) float f32x4;
typedef __attribute__((ext_vector_type(8))) short bf16x8;

__device__ __forceinline__ float bf2f(unsigned int u16) {
    return __uint_as_float(u16 << 16);
}
__device__ __forceinline__ unsigned short f2bf(float f) {
    unsigned int u = __float_as_uint(f);
    u += 0x7fffu + ((u >> 16) & 1u);   // RNE
    return (unsigned short)(u >> 16);
}
__device__ __forceinline__ unsigned int pack2(float a, float b) {
    return (unsigned int)f2bf(a) | ((unsigned int)f2bf(b) << 16);
}

// ---------------- fused degree + ELL bucket, dst-range partitioned ----------------
__global__ __launch_bounds__(256) void k_fill(const int* __restrict__ rows,
                                              const int* __restrict__ cols,
                                              int* __restrict__ deg,
                                              int* __restrict__ ell,
                                              int E, int perBlock, int R) {
    int g  = blockIdx.x & (GPART - 1);
    int cb = blockIdx.x >> 3;
    int lo = g * R, hi = lo + R;
    int eBeg = cb * perBlock;
    int eEnd = eBeg + perBlock; if (eEnd > E) eEnd = E;
    for (int e = eBeg + threadIdx.x; e < eEnd; e += 256) {
        int c = cols[e];
        if (c >= lo && c < hi) {
            int r = rows[e];
            int k = atomicAdd(&deg[c], 1);
            if (k < ELLW) ell[(size_t)c * ELLW + k] = r;
        }
    }
}

__global__ void k_dinv(const int* __restrict__ deg, float* __restrict__ dinv, int N) {
    int i = blockIdx.x * blockDim.x + threadIdx.x;
    if (i < N) dinv[i] = rsqrtf((float)(deg[i] + 1));
}

// ---------------- pack W1/W2 into MFMA B-fragment order, bf16 ----------------
__global__ __launch_bounds__(256) void k_packW(const float* __restrict__ W1,
                                               const float* __restrict__ W2,
                                               unsigned short* __restrict__ w1p,
                                               unsigned short* __restrict__ w2p) {
    int id = blockIdx.x * 256 + threadIdx.x;
    if (id < 2048) {                     // W1: 8 n-tiles x 4 k-steps x 64 lanes
        int lane = id & 63, s = (id >> 6) & 3, t = id >> 8;
        int n = t * 16 + (lane & 15);
        int k0 = s * 32 + (lane >> 4) * 8;
#pragma unroll
        for (int j = 0; j < 8; ++j)
            w1p[(size_t)id * 8 + j] = f2bf(W1[(k0 + j) * DHID + n]);
    } else if (id < 3072) {              // W2: 4 n-tiles x 4 k-steps x 64 lanes
        int id2 = id - 2048;
        int lane = id2 & 63, s = (id2 >> 6) & 3, t = id2 >> 8;
        int n = t * 16 + (lane & 15);
        int k0 = s * 32 + (lane >> 4) * 8;
#pragma unroll
        for (int j = 0; j < 8; ++j)
            w2p[(size_t)id2 * 8 + j] = f2bf(W2[(k0 + j) * DOUT + n]);
    }
}

// ---------------- GEMM1 (MFMA): h1b[N,128] bf16 = bf16(x) @ bf16(W1) ----------------
__global__ __launch_bounds__(256) void k_gemm1(const float* __restrict__ x,
                                               const unsigned short* __restrict__ w1p,
                                               unsigned short* __restrict__ h1b, int N) {
    int wave = threadIdx.x >> 6, lane = threadIdx.x & 63;
    int quad = lane >> 4, qr = lane & 15;
    int rowBase = blockIdx.x * 64 + wave * 16;
    int arow = rowBase + qr;
    bool rowOK = arow < N;
    f32x4 acc[8] = {};
#pragma unroll
    for (int s = 0; s < 4; ++s) {
        bf16x8 a = {};
        if (rowOK) {
            const float* ap = x + (size_t)arow * DIN + s * 32 + quad * 8;
            float4 lo = *(const float4*)ap;
            float4 hi = *(const float4*)(ap + 4);
            a[0] = (short)f2bf(lo.x); a[1] = (short)f2bf(lo.y);
            a[2] = (short)f2bf(lo.z); a[3] = (short)f2bf(lo.w);
            a[4] = (short)f2bf(hi.x); a[5] = (short)f2bf(hi.y);
            a[6] = (short)f2bf(hi.z); a[7] = (short)f2bf(hi.w);
        }
#pragma unroll
        for (int t = 0; t < 8; ++t) {
            bf16x8 b = *(const bf16x8*)(w1p + ((size_t)(t * 4 + s) * 64 + lane) * 8);
            acc[t] = __builtin_amdgcn_mfma_f32_16x16x32_bf16(a, b, acc[t], 0, 0, 0);
        }
    }
#pragma unroll
    for (int t = 0; t < 8; ++t)
#pragma unroll
        for (int i = 0; i < 4; ++i) {
            int r = rowBase + quad * 4 + i;
            if (r < N) h1b[(size_t)r * DHID + t * 16 + qr] = f2bf(acc[t][i]);
        }
}

// ---------------- gather layer 1 + fused bias/self-loop/relu -> bf16 hact ----------------
// one wave per dst node; ELL row and dinv preloaded per-lane, __shfl-broadcast
__global__ __launch_bounds__(256) void k_gather1(const int* __restrict__ deg,
                                                 const int* __restrict__ ell,
                                                 const float* __restrict__ dinv,
                                                 const unsigned int* __restrict__ h1u,
                                                 const float* __restrict__ b1,
                                                 unsigned int* __restrict__ hactu, int N) {
    int w = (blockIdx.x * 256 + threadIdx.x) >> 6;
    int lane = threadIdx.x & 63;
    if (w >= N) return;
    int d = deg[w]; if (d > ELLW) d = ELLW;
    int iv = ell[(size_t)w * ELLW + lane];          // 256B coalesced row load
    float dv = (lane < d) ? dinv[iv] : 0.f;         // per-lane weight gather
    float a0 = 0.f, a1 = 0.f;
    int e = 0;
    for (; e + 4 <= d; e += 4) {
        int s0 = __shfl(iv, e + 0), s1 = __shfl(iv, e + 1);
        int s2 = __shfl(iv, e + 2), s3 = __shfl(iv, e + 3);
        float w0 = __shfl(dv, e + 0), w1 = __shfl(dv, e + 1);
        float w2 = __shfl(dv, e + 2), w3 = __shfl(dv, e + 3);
        unsigned int v0 = h1u[(size_t)s0 * 64 + lane];
        unsigned int v1 = h1u[(size_t)s1 * 64 + lane];
        unsigned int v2 = h1u[(size_t)s2 * 64 + lane];
        unsigned int v3 = h1u[(size_t)s3 * 64 + lane];
        a0 = fmaf(w0, bf2f(v0 & 0xffffu), a0); a1 = fmaf(w0, bf2f(v0 >> 16), a1);
        a0 = fmaf(w1, bf2f(v1 & 0xffffu), a0); a1 = fmaf(w1, bf2f(v1 >> 16), a1);
        a0 = fmaf(w2, bf2f(v2 & 0xffffu), a0); a1 = fmaf(w2, bf2f(v2 >> 16), a1);
        a0 = fmaf(w3, bf2f(v3 & 0xffffu), a0); a1 = fmaf(w3, bf2f(v3 >> 16), a1);
    }
    for (; e < d; ++e) {
        int s0 = __shfl(iv, e);
        float w0 = __shfl(dv, e);
        unsigned int v0 = h1u[(size_t)s0 * 64 + lane];
        a0 = fmaf(w0, bf2f(v0 & 0xffffu), a0); a1 = fmaf(w0, bf2f(v0 >> 16), a1);
    }
    float di = dinv[w], self = di * di;
    unsigned int hv = h1u[(size_t)w * 64 + lane];
    float2 bv = *(const float2*)(b1 + 2 * lane);
    float r0 = fmaf(di, a0, fmaf(self, bf2f(hv & 0xffffu), bv.x));
    float r1 = fmaf(di, a1, fmaf(self, bf2f(hv >> 16), bv.y));
    hactu[(size_t)w * 64 + lane] = pack2(fmaxf(r0, 0.f), fmaxf(r1, 0.f));
}

// ---------------- GEMM2 (MFMA): h2b[N,64] bf16 = hact(bf16) @ bf16(W2) ----------------
__global__ __launch_bounds__(256) void k_gemm2(const unsigned short* __restrict__ hactb,
                                               const unsigned short* __restrict__ w2p,
                                               unsigned short* __restrict__ h2b, int N) {
    int wave = threadIdx.x >> 6, lane = threadIdx.x & 63;
    int quad = lane >> 4, qr = lane & 15;
    int rowBase = blockIdx.x * 64 + wave * 16;
    int arow = rowBase + qr;
    bool rowOK = arow < N;
    f32x4 acc[4] = {};
#pragma unroll
    for (int s = 0; s < 4; ++s) {
        bf16x8 a = {};
        if (rowOK) a = *(const bf16x8*)(hactb + (size_t)arow * DHID + s * 32 + quad * 8);
#pragma unroll
        for (int t = 0; t < 4; ++t) {
            bf16x8 b = *(const bf16x8*)(w2p + ((size_t)(t * 4 + s) * 64 + lane) * 8);
            acc[t] = __builtin_amdgcn_mfma_f32_16x16x32_bf16(a, b, acc[t], 0, 0, 0);
        }
    }
#pragma unroll
    for (int t = 0; t < 4; ++t)
#pragma unroll
        for (int i = 0; i < 4; ++i) {
            int r = rowBase + quad * 4 + i;
            if (r < N) h2b[(size_t)r * DOUT + t * 16 + qr] = f2bf(acc[t][i]);
        }
}

// ---------------- gather layer 2 + fused bias/self-loop; writes d_out (f32) ----------------
__global__ __launch_bounds__(256) void k_gather2(const int* __restrict__ deg,
                                                 const int* __restrict__ ell,
                                                 const float* __restrict__ dinv,
                                                 const unsigned short* __restrict__ h2u,
                                                 const float* __restrict__ b2,
                                                 float* __restrict__ out, int N) {
    int w = (blockIdx.x * 256 + threadIdx.x) >> 6;
    int lane = threadIdx.x & 63;
    if (w >= N) return;
    int d = deg[w]; if (d > ELLW) d = ELLW;
    int iv = ell[(size_t)w * ELLW + lane];
    float dv = (lane < d) ? dinv[iv] : 0.f;
    float a = 0.f;
    int e = 0;
    for (; e + 4 <= d; e += 4) {
        int s0 = __shfl(iv, e + 0), s1 = __shfl(iv, e + 1);
        int s2 = __shfl(iv, e + 2), s3 = __shfl(iv, e + 3);
        float w0 = __shfl(dv, e + 0), w1 = __shfl(dv, e + 1);
        float w2 = __shfl(dv, e + 2), w3 = __shfl(dv, e + 3);
        float v0 = bf2f((unsigned int)h2u[(size_t)s0 * DOUT + lane]);
        float v1 = bf2f((unsigned int)h2u[(size_t)s1 * DOUT + lane]);
        float v2 = bf2f((unsigned int)h2u[(size_t)s2 * DOUT + lane]);
        float v3 = bf2f((unsigned int)h2u[(size_t)s3 * DOUT + lane]);
        a = fmaf(w0, v0, a); a = fmaf(w1, v1, a);
        a = fmaf(w2, v2, a); a = fmaf(w3, v3, a);
    }
    for (; e < d; ++e) {
        int s0 = __shfl(iv, e);
        float w0 = __shfl(dv, e);
        a = fmaf(w0, bf2f((unsigned int)h2u[(size_t)s0 * DOUT + lane]), a);
    }
    float di = dinv[w], self = di * di;
    float hv = bf2f((unsigned int)h2u[(size_t)w * DOUT + lane]);
    out[(size_t)w * DOUT + lane] = fmaf(di, a, fmaf(self, hv, b2[lane]));
}

extern "C" void kernel_launch(void* const* d_in, const int* in_sizes, int n_in,
                              void* d_out, int out_size, void* d_ws, size_t ws_size,
                              hipStream_t stream) {
    const float* x  = (const float*)d_in[0];
    const int*   ei = (const int*)d_in[1];
    const float* W1 = (const float*)d_in[2];
    const float* b1 = (const float*)d_in[3];
    const float* W2 = (const float*)d_in[4];
    const float* b2 = (const float*)d_in[5];

    const int N = in_sizes[0] / DIN;     // 100000
    const int E = in_sizes[1] / 2;       // 1600000
    const int* rows = ei;                // sources
    const int* cols = ei + E;            // destinations

    // workspace (~78 MB)
    char* p = (char*)d_ws;
    int*   ell  = (int*)p;                  p += (size_t)N * ELLW * 4;   // 25.6 MB
    unsigned short* h1b = (unsigned short*)p; p += (size_t)N * DHID * 2; // 25.6 MB
    unsigned short* hactb = (unsigned short*)p; p += (size_t)N * DHID * 2; // 25.6 MB
    unsigned short* w1p = (unsigned short*)p; p += (size_t)2048 * 8 * 2; // 32 KB
    unsigned short* w2p = (unsigned short*)p; p += (size_t)1024 * 8 * 2; // 16 KB
    int*   deg  = (int*)p;                  p += (size_t)N * 4;
    float* dinv = (float*)p;                p += (size_t)N * 4;
    unsigned short* h2b = h1b;   // alias: h1 dead after k_gather1

    const int R = (N + GPART - 1) / GPART;
    const int perBlock = (E + BPG - 1) / BPG;

    // adjacency build
    hipMemsetAsync(deg, 0, (size_t)N * 4, stream);
    k_fill<<<GPART * BPG, 256, 0, stream>>>(rows, cols, deg, ell, E, perBlock, R);
    k_dinv<<<(N + 255) / 256, 256, 0, stream>>>(deg, dinv, N);
    k_packW<<<12, 256, 0, stream>>>(W1, W2, w1p, w2p);

    // layer 1
    k_gemm1<<<(N + 63) / 64, 256, 0, stream>>>(x, w1p, h1b, N);
    k_gather1<<<(N + 3) / 4, 256, 0, stream>>>(deg, ell, dinv, (const unsigned int*)h1b,
                                               b1, (unsigned int*)hactb, N);

    // layer 2
    k_gemm2<<<(N + 63) / 64, 256, 0, stream>>>(hactb, w2p, h2b, N);
    k_gather2<<<(N + 3) / 4, 256, 0, stream>>>(deg, ell, dinv, h2b, b2, (float*)d_out, N);
}

// Round 8
// 312.368 us; speedup vs baseline: 4.2005x; 1.0293x over previous
//
#include <hip/hip_runtime.h>

// GCN 2-layer forward. f32 wire; bf16 MFMA GEMMs (f32 acc); bf16 gather tables;
// padded-ELL adjacency. This round: fill+gemm1 fused (block specialization),
// int4 edge scan in fill, rsqrt-on-the-fly (no dinv pass), 8-wide gather MLP.

#define DIN 128
#define DHID 128
#define DOUT 64
#define ELLW 64     // max in-degree (Poisson(16): P(>=64) ~ 1e-22)
#define GPART 8
#define BPG 256

typedef __attribute__((ext_vector_type(4))) float f32x4;
typedef __attribute__((ext_vector_type(8))) short bf16x8;

__device__ __forceinline__ float bf2f(unsigned int u16) {
    return __uint_as_float(u16 << 16);
}
__device__ __forceinline__ unsigned short f2bf(float f) {
    unsigned int u = __float_as_uint(f);
    u += 0x7fffu + ((u >> 16) & 1u);   // RNE
    return (unsigned short)(u >> 16);
}
__device__ __forceinline__ unsigned int pack2(float a, float b) {
    return (unsigned int)f2bf(a) | ((unsigned int)f2bf(b) << 16);
}

// ---------------- pack W1/W2 into MFMA B-fragment order, bf16 ----------------
__global__ __launch_bounds__(256) void k_packW(const float* __restrict__ W1,
                                               const float* __restrict__ W2,
                                               unsigned short* __restrict__ w1p,
                                               unsigned short* __restrict__ w2p) {
    int id = blockIdx.x * 256 + threadIdx.x;
    if (id < 2048) {                     // W1: 8 n-tiles x 4 k-steps x 64 lanes
        int lane = id & 63, s = (id >> 6) & 3, t = id >> 8;
        int n = t * 16 + (lane & 15);
        int k0 = s * 32 + (lane >> 4) * 8;
#pragma unroll
        for (int j = 0; j < 8; ++j)
            w1p[(size_t)id * 8 + j] = f2bf(W1[(k0 + j) * DHID + n]);
    } else if (id < 3072) {              // W2: 4 n-tiles x 4 k-steps x 64 lanes
        int id2 = id - 2048;
        int lane = id2 & 63, s = (id2 >> 6) & 3, t = id2 >> 8;
        int n = t * 16 + (lane & 15);
        int k0 = s * 32 + (lane >> 4) * 8;
#pragma unroll
        for (int j = 0; j < 8; ++j)
            w2p[(size_t)id2 * 8 + j] = f2bf(W2[(k0 + j) * DOUT + n]);
    }
}

// ---------------- fused: ELL fill (blocks < FB) + GEMM1 (blocks >= FB) ----------------
__device__ __forceinline__ void fill_edge(int c, int r, int lo, int hi,
                                          int* __restrict__ deg, int* __restrict__ ell) {
    if (c >= lo && c < hi) {
        int k = atomicAdd(&deg[c], 1);
        if (k < ELLW) ell[(size_t)c * ELLW + k] = r;
    }
}

__global__ __launch_bounds__(256) void k_fill_gemm1(
        const int* __restrict__ rows, const int* __restrict__ cols,
        int* __restrict__ deg, int* __restrict__ ell,
        int E, int perBlock, int R, int FB,
        const float* __restrict__ x, const unsigned short* __restrict__ w1p,
        unsigned short* __restrict__ h1b, int N) {
    if ((int)blockIdx.x < FB) {
        // ----- ELL fill, dst-range partitioned, int4 edge scan -----
        int g  = blockIdx.x & (GPART - 1);
        int cb = blockIdx.x >> 3;
        int lo = g * R, hi = lo + R;
        int eBeg = cb * perBlock;
        int eEnd = eBeg + perBlock; if (eEnd > E) eEnd = E;
        for (int e = eBeg + 4 * threadIdx.x; e < eEnd; e += 4 * 256) {
            if (e + 3 < eEnd) {
                int4 c4 = *(const int4*)(cols + e);
                int4 r4 = *(const int4*)(rows + e);
                fill_edge(c4.x, r4.x, lo, hi, deg, ell);
                fill_edge(c4.y, r4.y, lo, hi, deg, ell);
                fill_edge(c4.z, r4.z, lo, hi, deg, ell);
                fill_edge(c4.w, r4.w, lo, hi, deg, ell);
            } else {
                for (int j = e; j < eEnd; ++j) fill_edge(cols[j], rows[j], lo, hi, deg, ell);
            }
        }
        return;
    }
    // ----- GEMM1 (MFMA): h1b[N,128] bf16 = bf16(x) @ w1p -----
    int bid = blockIdx.x - FB;
    int wave = threadIdx.x >> 6, lane = threadIdx.x & 63;
    int quad = lane >> 4, qr = lane & 15;
    int rowBase = bid * 64 + wave * 16;
    int arow = rowBase + qr;
    bool rowOK = arow < N;
    f32x4 acc[8] = {};
#pragma unroll
    for (int s = 0; s < 4; ++s) {
        bf16x8 a = {};
        if (rowOK) {
            const float* ap = x + (size_t)arow * DIN + s * 32 + quad * 8;
            float4 lo = *(const float4*)ap;
            float4 hi = *(const float4*)(ap + 4);
            a[0] = (short)f2bf(lo.x); a[1] = (short)f2bf(lo.y);
            a[2] = (short)f2bf(lo.z); a[3] = (short)f2bf(lo.w);
            a[4] = (short)f2bf(hi.x); a[5] = (short)f2bf(hi.y);
            a[6] = (short)f2bf(hi.z); a[7] = (short)f2bf(hi.w);
        }
#pragma unroll
        for (int t = 0; t < 8; ++t) {
            bf16x8 b = *(const bf16x8*)(w1p + ((size_t)(t * 4 + s) * 64 + lane) * 8);
            acc[t] = __builtin_amdgcn_mfma_f32_16x16x32_bf16(a, b, acc[t], 0, 0, 0);
        }
    }
#pragma unroll
    for (int t = 0; t < 8; ++t)
#pragma unroll
        for (int i = 0; i < 4; ++i) {
            int r = rowBase + quad * 4 + i;
            if (r < N) h1b[(size_t)r * DHID + t * 16 + qr] = f2bf(acc[t][i]);
        }
}

// ---------------- gather layer 1 + fused bias/self-loop/relu -> bf16 hact ----------------
// one wave per dst node; ELL row + weight preloaded per-lane, __shfl-broadcast;
// 8 row-gathers in flight.
__global__ __launch_bounds__(256) void k_gather1(const int* __restrict__ deg,
                                                 const int* __restrict__ ell,
                                                 const unsigned int* __restrict__ h1u,
                                                 const float* __restrict__ b1,
                                                 unsigned int* __restrict__ hactu, int N) {
    int w = (blockIdx.x * 256 + threadIdx.x) >> 6;
    int lane = threadIdx.x & 63;
    if (w >= N) return;
    int d = deg[w]; if (d > ELLW) d = ELLW;
    int iv = ell[(size_t)w * ELLW + lane];                      // 256B coalesced
    float dv = (lane < d) ? rsqrtf((float)(deg[iv] + 1)) : 0.f; // per-lane weight
    float a0 = 0.f, a1 = 0.f;
    int e = 0;
    for (; e + 8 <= d; e += 8) {
        int s[8]; float wg[8]; unsigned int v[8];
#pragma unroll
        for (int j = 0; j < 8; ++j) { s[j] = __shfl(iv, e + j); wg[j] = __shfl(dv, e + j); }
#pragma unroll
        for (int j = 0; j < 8; ++j) v[j] = h1u[(size_t)s[j] * 64 + lane];
#pragma unroll
        for (int j = 0; j < 8; ++j) {
            a0 = fmaf(wg[j], bf2f(v[j] & 0xffffu), a0);
            a1 = fmaf(wg[j], bf2f(v[j] >> 16), a1);
        }
    }
    for (; e + 4 <= d; e += 4) {
        int s[4]; float wg[4]; unsigned int v[4];
#pragma unroll
        for (int j = 0; j < 4; ++j) { s[j] = __shfl(iv, e + j); wg[j] = __shfl(dv, e + j); }
#pragma unroll
        for (int j = 0; j < 4; ++j) v[j] = h1u[(size_t)s[j] * 64 + lane];
#pragma unroll
        for (int j = 0; j < 4; ++j) {
            a0 = fmaf(wg[j], bf2f(v[j] & 0xffffu), a0);
            a1 = fmaf(wg[j], bf2f(v[j] >> 16), a1);
        }
    }
    for (; e < d; ++e) {
        int s0 = __shfl(iv, e);
        float w0 = __shfl(dv, e);
        unsigned int v0 = h1u[(size_t)s0 * 64 + lane];
        a0 = fmaf(w0, bf2f(v0 & 0xffffu), a0); a1 = fmaf(w0, bf2f(v0 >> 16), a1);
    }
    float di = rsqrtf((float)(d + 1)), self = di * di;
    unsigned int hv = h1u[(size_t)w * 64 + lane];
    float2 bv = *(const float2*)(b1 + 2 * lane);
    float r0 = fmaf(di, a0, fmaf(self, bf2f(hv & 0xffffu), bv.x));
    float r1 = fmaf(di, a1, fmaf(self, bf2f(hv >> 16), bv.y));
    hactu[(size_t)w * 64 + lane] = pack2(fmaxf(r0, 0.f), fmaxf(r1, 0.f));
}

// ---------------- GEMM2 (MFMA): h2b[N,64] bf16 = hact(bf16) @ w2p ----------------
__global__ __launch_bounds__(256) void k_gemm2(const unsigned short* __restrict__ hactb,
                                               const unsigned short* __restrict__ w2p,
                                               unsigned short* __restrict__ h2b, int N) {
    int wave = threadIdx.x >> 6, lane = threadIdx.x & 63;
    int quad = lane >> 4, qr = lane & 15;
    int rowBase = blockIdx.x * 64 + wave * 16;
    int arow = rowBase + qr;
    bool rowOK = arow < N;
    f32x4 acc[4] = {};
#pragma unroll
    for (int s = 0; s < 4; ++s) {
        bf16x8 a = {};
        if (rowOK) a = *(const bf16x8*)(hactb + (size_t)arow * DHID + s * 32 + quad * 8);
#pragma unroll
        for (int t = 0; t < 4; ++t) {
            bf16x8 b = *(const bf16x8*)(w2p + ((size_t)(t * 4 + s) * 64 + lane) * 8);
            acc[t] = __builtin_amdgcn_mfma_f32_16x16x32_bf16(a, b, acc[t], 0, 0, 0);
        }
    }
#pragma unroll
    for (int t = 0; t < 4; ++t)
#pragma unroll
        for (int i = 0; i < 4; ++i) {
            int r = rowBase + quad * 4 + i;
            if (r < N) h2b[(size_t)r * DOUT + t * 16 + qr] = f2bf(acc[t][i]);
        }
}

// ---------------- gather layer 2 + fused bias/self-loop; writes d_out (f32) ----------------
__global__ __launch_bounds__(256) void k_gather2(const int* __restrict__ deg,
                                                 const int* __restrict__ ell,
                                                 const unsigned short* __restrict__ h2u,
                                                 const float* __restrict__ b2,
                                                 float* __restrict__ out, int N) {
    int w = (blockIdx.x * 256 + threadIdx.x) >> 6;
    int lane = threadIdx.x & 63;
    if (w >= N) return;
    int d = deg[w]; if (d > ELLW) d = ELLW;
    int iv = ell[(size_t)w * ELLW + lane];
    float dv = (lane < d) ? rsqrtf((float)(deg[iv] + 1)) : 0.f;
    float a = 0.f;
    int e = 0;
    for (; e + 8 <= d; e += 8) {
        int s[8]; float wg[8]; float v[8];
#pragma unroll
        for (int j = 0; j < 8; ++j) { s[j] = __shfl(iv, e + j); wg[j] = __shfl(dv, e + j); }
#pragma unroll
        for (int j = 0; j < 8; ++j) v[j] = bf2f((unsigned int)h2u[(size_t)s[j] * DOUT + lane]);
#pragma unroll
        for (int j = 0; j < 8; ++j) a = fmaf(wg[j], v[j], a);
    }
    for (; e + 4 <= d; e += 4) {
        int s[4]; float wg[4]; float v[4];
#pragma unroll
        for (int j = 0; j < 4; ++j) { s[j] = __shfl(iv, e + j); wg[j] = __shfl(dv, e + j); }
#pragma unroll
        for (int j = 0; j < 4; ++j) v[j] = bf2f((unsigned int)h2u[(size_t)s[j] * DOUT + lane]);
#pragma unroll
        for (int j = 0; j < 4; ++j) a = fmaf(wg[j], v[j], a);
    }
    for (; e < d; ++e) {
        int s0 = __shfl(iv, e);
        float w0 = __shfl(dv, e);
        a = fmaf(w0, bf2f((unsigned int)h2u[(size_t)s0 * DOUT + lane]), a);
    }
    float di = rsqrtf((float)(d + 1)), self = di * di;
    float hv = bf2f((unsigned int)h2u[(size_t)w * DOUT + lane]);
    out[(size_t)w * DOUT + lane] = fmaf(di, a, fmaf(self, hv, b2[lane]));
}

extern "C" void kernel_launch(void* const* d_in, const int* in_sizes, int n_in,
                              void* d_out, int out_size, void* d_ws, size_t ws_size,
                              hipStream_t stream) {
    const float* x  = (const float*)d_in[0];
    const int*   ei = (const int*)d_in[1];
    const float* W1 = (const float*)d_in[2];
    const float* b1 = (const float*)d_in[3];
    const float* W2 = (const float*)d_in[4];
    const float* b2 = (const float*)d_in[5];

    const int N = in_sizes[0] / DIN;     // 100000
    const int E = in_sizes[1] / 2;       // 1600000
    const int* rows = ei;                // sources
    const int* cols = ei + E;            // destinations

    // workspace (~77.5 MB)
    char* p = (char*)d_ws;
    int*   ell  = (int*)p;                    p += (size_t)N * ELLW * 4;   // 25.6 MB
    unsigned short* h1b = (unsigned short*)p;   p += (size_t)N * DHID * 2; // 25.6 MB
    unsigned short* hactb = (unsigned short*)p; p += (size_t)N * DHID * 2; // 25.6 MB
    unsigned short* w1p = (unsigned short*)p;   p += (size_t)2048 * 8 * 2; // 32 KB
    unsigned short* w2p = (unsigned short*)p;   p += (size_t)1024 * 8 * 2; // 16 KB
    int*   deg  = (int*)p;                    p += (size_t)N * 4;
    unsigned short* h2b = h1b;   // alias: h1 dead after k_gather1

    const int R = (N + GPART - 1) / GPART;
    int perBlock = (E + BPG - 1) / BPG;
    perBlock = (perBlock + 3) & ~3;                  // int4-aligned chunks
    const int FB = GPART * BPG;                      // 2048 fill blocks
    const int GB = (N + 63) / 64;                    // 1563 gemm blocks

    k_packW<<<12, 256, 0, stream>>>(W1, W2, w1p, w2p);
    hipMemsetAsync(deg, 0, (size_t)N * 4, stream);

    // fill + gemm1 fused (independent work, concurrent blocks)
    k_fill_gemm1<<<FB + GB, 256, 0, stream>>>(rows, cols, deg, ell, E, perBlock, R, FB,
                                              x, w1p, h1b, N);

    // layer 1 aggregate
    k_gather1<<<(N + 3) / 4, 256, 0, stream>>>(deg, ell, (const unsigned int*)h1b,
                                               b1, (unsigned int*)hactb, N);

    // layer 2
    k_gemm2<<<(N + 63) / 64, 256, 0, stream>>>(hactb, w2p, h2b, N);
    k_gather2<<<(N + 3) / 4, 256, 0, stream>>>(deg, ell, h2b, b2, (float*)d_out, N);
}